// Round 10
// baseline (481.200 us; speedup 1.0000x reference)
//
#include <hip/hip_runtime.h>

// SparseMinCostFlow — SINGLE mega-dispatch: sorts ∥ 256-wide chain → reg-direct scatter.
// N=8192, E=262144, 10 flow iters, dense NxN fp32 out (256 MB).
//
// r9 accounting: total 343 = harness poison fills (~204, fixed) + mega ~139
// (sort ~25 + chain ~30 + scatter ~60 + transitions). r10:
//  - scatter: NO LDS image. Thread owns 8 fixed cols; per row ~32 broadcast
//    LDS edge reads + 8 cmp-selects, then 2 coalesced float4 stores. No
//    per-row barriers at all -> stores stream at HBM BW. Group edges are
//    counting-sorted by row-local (32 buckets) in LDS, premultiplied by a9.
//  - sorts: 64 blocks/team (4 edges/thread), cnt 64x256 -> sort ~2x faster.
//  - chain: unchanged from r9 (256 blocks, 1-2 reg edges/thread, per stage:
//    adj gathers + 32-col LDS acc + 32-float publish + 256-party barrier).
// Uniform pre-scatter prereqs (r7 tripwire lesson): stage-9 256-party
// barrier (adj9f) + all-64 flagsR2 (se2/gstart).
// All cross-block data agent-scope (ws re-poisoned each iter => plain reads
// could hit stale 0xAA in L2). Grid=256, LDS ~69KB => >=2 blk/CU capacity,
// all 256 co-resident (required for flag barriers).

#define NN 8192
#define EE 262144
#define THREADS 1024
#define SORTB 64                 // blocks per sort team
#define EPB (EE / SORTB)         // 4096 edges per sort block (4/thread)
#define NB 256                   // buckets = groups = chain blocks
#define CPB (NN / NB)            // 32 cols per chain block
#define GROWS 32                 // rows per scatter group
#define ECAP 2048                // LDS edge capacity per group (mean 1024)
#define NBLK 256
#define MAGIC 0x5CA1AB1Eu        // != 0xAAAAAAAA ws poison, != 0

typedef unsigned long long u64;

#define LOAD_AU(p)    __hip_atomic_load((p),  __ATOMIC_RELAXED, __HIP_MEMORY_SCOPE_AGENT)
#define STORE_AU(p,v) __hip_atomic_store((p), (v), __ATOMIC_RELAXED, __HIP_MEMORY_SCOPE_AGENT)

// LDS arena: one member live at a time (phases separated by barriers/syncs).
union SM {
    struct { unsigned cnt[SORTB * NB]; unsigned hist[NB]; unsigned bst[NB + 1];
             unsigned offs[NB]; } so;                                   // ~69 KB
    struct { float acc[CPB]; float dem[CPB]; } c;                       // 256 B
    struct { u64 eL[ECAP]; u64 eL2[ECAP]; unsigned hist[32];
             unsigned rs[GROWS + 1]; unsigned offs[32]; } s;            // ~33 KB
};

// nblk(<=64)-party: set own word + poll (caller __syncthreads first: vmcnt drain).
__device__ __forceinline__ void flag_barrier_n(unsigned* fl, int idx, int tid, int nblk) {
    if (tid == 0) STORE_AU(&fl[idx], MAGIC);
    asm volatile("" ::: "memory");
    if (tid < 64) {
        for (;;) {
            unsigned f = (tid < nblk) ? LOAD_AU(&fl[tid]) : MAGIC;
            if (__all(f == MAGIC)) break;
            __builtin_amdgcn_s_sleep(2);
        }
    }
    asm volatile("" ::: "memory");
    __syncthreads();
}

// 256-party: set own word + poll 4 words/lane.
__device__ __forceinline__ void flag_barrier_256(unsigned* fl, int idx, int tid) {
    if (tid == 0) STORE_AU(&fl[idx], MAGIC);
    asm volatile("" ::: "memory");
    if (tid < 64) {
        for (;;) {
            unsigned a = LOAD_AU(&fl[tid]);
            unsigned b = LOAD_AU(&fl[tid + 64]);
            unsigned c = LOAD_AU(&fl[tid + 128]);
            unsigned d = LOAD_AU(&fl[tid + 192]);
            if (__all(a == MAGIC && b == MAGIC && c == MAGIC && d == MAGIC)) break;
            __builtin_amdgcn_s_sleep(2);
        }
    }
    asm volatile("" ::: "memory");
    __syncthreads();
}

// passive wait on nblk(<=64) words. SLP: s_sleep ticks, compile-time literal.
template <int SLP>
__device__ __forceinline__ void wait_flags_n(unsigned* fl, int tid, int nblk) {
    if (tid < 64) {
        for (;;) {
            unsigned f = (tid < nblk) ? LOAD_AU(&fl[tid]) : MAGIC;
            if (__all(f == MAGIC)) break;
            __builtin_amdgcn_s_sleep(SLP);
        }
    }
    asm volatile("" ::: "memory");
    __syncthreads();
}

__global__ void __launch_bounds__(THREADS) mega(
        const float* __restrict__ values, const float* __restrict__ dem,
        const int* __restrict__ rows, const int* __restrict__ cols,
        u64* __restrict__ se,        // EE col-sorted: row13 | coff5<<13 | v<<32
        u64* __restrict__ se2,       // EE row-sorted: col13 | rl5<<13  | v<<32
        float* __restrict__ adjF,    // 9*NN floats (slots 1..8)
        float* __restrict__ adj9f,   // NN floats (= A10)
        unsigned* __restrict__ cnt,  // SORTB*NB
        unsigned* __restrict__ cnt2, // SORTB*NB
        unsigned* __restrict__ bstart,   // NB+1
        unsigned* __restrict__ gstart,   // NB+1
        unsigned* __restrict__ flagsC, unsigned* __restrict__ flagsR,
        unsigned* __restrict__ flagsE, unsigned* __restrict__ flagsR2,
        unsigned* __restrict__ flagsK,   // 9*NB
        float* __restrict__ out) {
    __shared__ SM sm;
    __shared__ float a9[GROWS];
    const int bid = blockIdx.x, tid = threadIdx.x;

    if (bid < SORTB) {
        // ============ col-sort team: bucket = col>>5 (256 buckets) ============
        if (tid < NB) sm.so.hist[tid] = 0;
        __syncthreads();
        const int4* c4 = (const int4*)(cols + bid * EPB);
        int4 ca = c4[tid];                            // 4 edges/thread
        atomicAdd(&sm.so.hist[ca.x >> 5], 1u);  atomicAdd(&sm.so.hist[ca.y >> 5], 1u);
        atomicAdd(&sm.so.hist[ca.z >> 5], 1u);  atomicAdd(&sm.so.hist[ca.w >> 5], 1u);
        __syncthreads();
        if (tid < NB) STORE_AU(&cnt[bid * NB + tid], sm.so.hist[tid]);
        __syncthreads();                              // drain cnt
        flag_barrier_n(flagsC, bid, tid, SORTB);

        #pragma unroll
        for (int j = 0; j < (SORTB * NB) / THREADS; ++j)
            sm.so.cnt[tid + j * THREADS] = LOAD_AU(&cnt[tid + j * THREADS]);
        __syncthreads();
        if (tid < NB) {
            unsigned t = 0;
            for (int b = 0; b < SORTB; ++b) t += sm.so.cnt[b * NB + tid];
            sm.so.hist[tid] = t;
        }
        __syncthreads();
        if (tid == 0) {
            unsigned run = 0;
            for (int k = 0; k < NB; ++k) { sm.so.bst[k] = run; run += sm.so.hist[k]; }
            sm.so.bst[NB] = run;
        }
        __syncthreads();
        if (tid < NB) {
            unsigned off = sm.so.bst[tid];
            for (int b = 0; b < bid; ++b) off += sm.so.cnt[b * NB + tid];
            sm.so.offs[tid] = off;
        }
        if (bid == 0 && tid <= NB) STORE_AU(&bstart[tid], sm.so.bst[tid]);
        __syncthreads();

        {   // push: meta = row | (col&31)<<13, value hi32
            const int4*   r4 = (const int4*)(rows + bid * EPB);
            const float4* v4 = (const float4*)(values + bid * EPB);
            int4 ra = r4[tid];  float4 va = v4[tid];
            #define PUSHC(R, C, V) do {                                        \
                unsigned dst_ = atomicAdd(&sm.so.offs[(C) >> 5], 1u);          \
                u64 w_ = (unsigned)((R) | (((C) & 31) << 13))                  \
                       | ((u64)__float_as_uint(V) << 32);                      \
                STORE_AU(&se[dst_], w_);                                       \
            } while (0)
            PUSHC(ra.x, ca.x, va.x);  PUSHC(ra.y, ca.y, va.y);
            PUSHC(ra.z, ca.z, va.z);  PUSHC(ra.w, ca.w, va.w);
            #undef PUSHC
        }
        __syncthreads();                              // drain se + bstart
        flag_barrier_n(flagsE, bid, tid, SORTB);      // col-sort complete
    } else if (bid < 2 * SORTB) {
        // ============ row-sort team: group = row>>5 (256 groups) ============
        const int b2 = bid - SORTB;
        if (tid < NB) sm.so.hist[tid] = 0;
        __syncthreads();
        const int4* r4 = (const int4*)(rows + b2 * EPB);
        int4 ra = r4[tid];
        atomicAdd(&sm.so.hist[ra.x >> 5], 1u);  atomicAdd(&sm.so.hist[ra.y >> 5], 1u);
        atomicAdd(&sm.so.hist[ra.z >> 5], 1u);  atomicAdd(&sm.so.hist[ra.w >> 5], 1u);
        __syncthreads();
        if (tid < NB) STORE_AU(&cnt2[b2 * NB + tid], sm.so.hist[tid]);
        __syncthreads();
        flag_barrier_n(flagsR, b2, tid, SORTB);

        #pragma unroll
        for (int j = 0; j < (SORTB * NB) / THREADS; ++j)
            sm.so.cnt[tid + j * THREADS] = LOAD_AU(&cnt2[tid + j * THREADS]);
        __syncthreads();
        if (tid < NB) {
            unsigned t = 0;
            for (int b = 0; b < SORTB; ++b) t += sm.so.cnt[b * NB + tid];
            sm.so.hist[tid] = t;
        }
        __syncthreads();
        if (tid == 0) {
            unsigned run = 0;
            for (int k = 0; k < NB; ++k) { sm.so.bst[k] = run; run += sm.so.hist[k]; }
            sm.so.bst[NB] = run;
        }
        __syncthreads();
        if (tid < NB) {
            unsigned off = sm.so.bst[tid];
            for (int b = 0; b < b2; ++b) off += sm.so.cnt[b * NB + tid];
            sm.so.offs[tid] = off;
        }
        if (b2 == 0 && tid <= NB) STORE_AU(&gstart[tid], sm.so.bst[tid]);
        __syncthreads();

        {   // push: meta = col | (row&31)<<13, value hi32
            const int4*   c4 = (const int4*)(cols + b2 * EPB);
            const float4* v4 = (const float4*)(values + b2 * EPB);
            int4 ca = c4[tid];  float4 va = v4[tid];
            #define PUSHR(R, C, V) do {                                        \
                unsigned dst_ = atomicAdd(&sm.so.offs[(R) >> 5], 1u);          \
                u64 w_ = (unsigned)((C) | (((R) & 31) << 13))                  \
                       | ((u64)__float_as_uint(V) << 32);                      \
                STORE_AU(&se2[dst_], w_);                                      \
            } while (0)
            PUSHR(ra.x, ca.x, va.x);  PUSHR(ra.y, ca.y, va.y);
            PUSHR(ra.z, ca.z, va.z);  PUSHR(ra.w, ca.w, va.w);
            #undef PUSHR
        }
        __syncthreads();                              // drain se2 + gstart
        if (tid == 0) STORE_AU(&flagsR2[b2], MAGIC);
        asm volatile("" ::: "memory");
        wait_flags_n<4>(flagsE, tid, SORTB);          // then join the chain
    } else {
        // ============ parked until col-sort done ============
        wait_flags_n<8>(flagsE, tid, SORTB);
    }

    // ================= chain: ALL 256 blocks, block owns bucket `bid` =======
    const int bs = (int)LOAD_AU(&bstart[bid]);
    const int be = (int)LOAD_AU(&bstart[bid + 1]);
    const int ne = be - bs;
    u64 e0 = 0, e1 = 0;                               // ~1024 edges -> 1-2 regs
    if (tid < ne)           e0 = LOAD_AU(&se[bs + tid]);
    if (THREADS + tid < ne) e1 = LOAD_AU(&se[bs + THREADS + tid]);
    if (tid < CPB) sm.c.dem[tid] = dem[bid * CPB + tid];

    for (int s = 1; s <= 9; ++s) {
        if (tid < CPB) sm.c.acc[tid] = 0.f;
        __syncthreads();

        #define EDGE(W) do {                                                   \
            unsigned m_ = (unsigned)(W);                                       \
            float v_ = __uint_as_float((unsigned)((W) >> 32));                 \
            int r_ = m_ & (NN - 1);                                            \
            float a_ = (s == 1) ? fmaxf(-dem[r_], 0.f)                         \
                                : LOAD_AU(&adjF[(size_t)(s - 1) * NN + r_]);   \
            atomicAdd(&sm.c.acc[(m_ >> 13) & 31], v_ * a_);                    \
        } while (0)
        if (tid < ne)           EDGE(e0);
        if (THREADS + tid < ne) EDGE(e1);
        for (int i = bs + 2 * THREADS + tid; i < be; i += THREADS) {  // ~never
            u64 w = LOAD_AU(&se[i]);
            EDGE(w);
        }
        #undef EDGE
        __syncthreads();

        if (tid < CPB) {
            float r = fmaxf(sm.c.acc[tid] - sm.c.dem[tid], 0.f);
            if (s < 9) STORE_AU(&adjF[(size_t)s * NN + bid * CPB + tid], r);
            else       STORE_AU(&adj9f[bid * CPB + tid], r);
        }
        __syncthreads();                              // drain publish
        flag_barrier_256(flagsK + (s - 1) * NB, bid, tid);
    }
    // stage-9 barrier == all adj9f visible. Uniform last prereq:
    wait_flags_n<2>(flagsR2, tid, SORTB);             // se2/gstart (long ready)

    // ====== scatter: block assembles row-group `bid` in REGISTERS ======
    {
        const int g = bid;
        const unsigned gs = LOAD_AU(&gstart[g]), ge = LOAD_AU(&gstart[g + 1]);
        const unsigned n = ge - gs;
        const unsigned ncp = n < (unsigned)ECAP ? n : (unsigned)ECAP;
        if (tid < GROWS) a9[tid] = LOAD_AU(&adj9f[g * GROWS + tid]);
        __syncthreads();                              // a9 + LDS transition

        for (unsigned i = tid; i < ncp; i += THREADS) {   // load + premultiply
            u64 w = LOAD_AU(&se2[gs + i]);
            unsigned m = (unsigned)w;
            float v = __uint_as_float((unsigned)(w >> 32)) * a9[(m >> 13) & 31];
            sm.s.eL[i] = (u64)m | ((u64)__float_as_uint(v) << 32);
        }
        if (tid < 32) sm.s.hist[tid] = 0;
        __syncthreads();
        for (unsigned i = tid; i < ncp; i += THREADS)     // hist by row-local
            atomicAdd(&sm.s.hist[((unsigned)sm.s.eL[i] >> 13) & 31], 1u);
        __syncthreads();
        if (tid == 0) {
            unsigned run = 0;
            for (int k = 0; k < 32; ++k) { sm.s.rs[k] = run; run += sm.s.hist[k]; }
            sm.s.rs[32] = run;
        }
        __syncthreads();
        if (tid < 32) sm.s.offs[tid] = sm.s.rs[tid];
        __syncthreads();
        for (unsigned i = tid; i < ncp; i += THREADS) {   // sort by row-local
            u64 w = sm.s.eL[i];
            unsigned dst = atomicAdd(&sm.s.offs[((unsigned)w >> 13) & 31], 1u);
            sm.s.eL2[dst] = w;
        }
        __syncthreads();

        // thread owns cols [4t,4t+4) and [4096+4t,4096+4t+4): coalesced float4
        const int cb0 = 4 * tid, cb1 = 4096 + 4 * tid;
        for (int r = 0; r < GROWS; ++r) {
            float x0 = 0.f, x1 = 0.f, x2 = 0.f, x3 = 0.f;
            float y0 = 0.f, y1 = 0.f, y2 = 0.f, y3 = 0.f;
            const unsigned s0 = sm.s.rs[r], s1 = sm.s.rs[r + 1];
            for (unsigned i = s0; i < s1; ++i) {          // ~32 broadcast reads
                u64 w = sm.s.eL2[i];
                int c = (int)((unsigned)w & (NN - 1));
                float v = __uint_as_float((unsigned)(w >> 32));
                x0 += (c == cb0)     ? v : 0.f;  x1 += (c == cb0 + 1) ? v : 0.f;
                x2 += (c == cb0 + 2) ? v : 0.f;  x3 += (c == cb0 + 3) ? v : 0.f;
                y0 += (c == cb1)     ? v : 0.f;  y1 += (c == cb1 + 1) ? v : 0.f;
                y2 += (c == cb1 + 2) ? v : 0.f;  y3 += (c == cb1 + 3) ? v : 0.f;
            }
            for (unsigned i = ECAP; i < n; ++i) {         // ~never (n>2048)
                u64 w = LOAD_AU(&se2[gs + i]);
                unsigned m = (unsigned)w;
                if (((m >> 13) & 31) == (unsigned)r) {
                    int c = (int)(m & (NN - 1));
                    float v = __uint_as_float((unsigned)(w >> 32)) * a9[r];
                    x0 += (c == cb0)     ? v : 0.f;  x1 += (c == cb0 + 1) ? v : 0.f;
                    x2 += (c == cb0 + 2) ? v : 0.f;  x3 += (c == cb0 + 3) ? v : 0.f;
                    y0 += (c == cb1)     ? v : 0.f;  y1 += (c == cb1 + 1) ? v : 0.f;
                    y2 += (c == cb1 + 2) ? v : 0.f;  y3 += (c == cb1 + 3) ? v : 0.f;
                }
            }
            float4* o4 = (float4*)(out + (size_t)(g * GROWS + r) * NN);
            o4[tid]        = make_float4(x0, x1, x2, x3);   // stores stream,
            o4[tid + 1024] = make_float4(y0, y1, y2, y3);   // no barriers
        }
    }
}

extern "C" void kernel_launch(void* const* d_in, const int* in_sizes, int n_in,
                              void* d_out, int out_size, void* d_ws, size_t ws_size,
                              hipStream_t stream) {
    const float* values = (const float*)d_in[0];
    const float* dem    = (const float*)d_in[1];
    const int*   rows   = (const int*)d_in[2];
    const int*   cols   = (const int*)d_in[3];
    float* out = (float*)d_out;

    u64*      se      = (u64*)d_ws;                       // 2 MB
    u64*      se2     = se + (size_t)EE;                  // 2 MB
    float*    adjF    = (float*)(se2 + (size_t)EE);       // 288 KB
    float*    adj9f   = adjF + 9L * NN;                   // 32 KB
    unsigned* cnt     = (unsigned*)(adj9f + NN);          // 64 KB
    unsigned* cnt2    = cnt + SORTB * NB;                 // 64 KB
    unsigned* bstart  = cnt2 + SORTB * NB;                // 257 (+pad)
    unsigned* gstart  = bstart + 320;                     // 257 (+pad)
    unsigned* flagsC  = gstart + 320;
    unsigned* flagsR  = flagsC + 64;
    unsigned* flagsE  = flagsR + 64;
    unsigned* flagsR2 = flagsE + 64;
    unsigned* flagsK  = flagsR2 + 64;                     // 9*256

    mega<<<NBLK, THREADS, 0, stream>>>(
        values, dem, rows, cols, se, se2, adjF, adj9f, cnt, cnt2,
        bstart, gstart, flagsC, flagsR, flagsE, flagsR2, flagsK, out);
}

// Round 11
// 342.823 us; speedup vs baseline: 1.4036x; 1.4036x over previous
//
#include <hip/hip_runtime.h>

// SparseMinCostFlow — SINGLE mega-dispatch: sorts ∥ 256-wide chain → LDS-img scatter.
// N=8192, E=262144, 10 flow iters, dense NxN fp32 out (256 MB).
//
// r10 post-mortem: register-direct scatter (broadcast scan + cmp-select) is a
// SERIAL dynamically-bounded LDS-latency chain (~1024 iter x ~150cyc/block) =>
// +144us regression. r9's LDS-image scatter (parallel ds_atomics + 2 raw
// barriers/row) was already near store-BW floor. r11 = r9 structure exactly,
// keeping only r10's 64-block sort teams (4 edges/thread, ~2x faster sort).
//
//  blocks 0..63  : col-sort (256 buckets, col>>5) -> flagsE -> chain -> scatter
//  blocks 64..127: row-sort (256 groups, row>>5) -> flagsR2 -> join chain
//  blocks 128..255: park until flagsE -> chain -> scatter
//  chain: all 256 blocks; block owns 32 cols; 1-2 reg edges/thread; per stage
//    adj GATHERS (agent) + 32-col LDS acc + 32-float publish + 256-party barrier.
//  scatter: block streams row-group bid; img double-buffer + raw s_barrier
//    (lgkmcnt only, no vmcnt drain) -> output stores stream at HBM BW.
// Uniform pre-scatter prereqs (r7 lesson): stage-9 256-party barrier (adj9f)
// + all-64 flagsR2 (se2/gstart). All cross-block data agent-scope (ws is
// re-poisoned each iter => plain reads could hit stale 0xAA in L2).
// Grid=256=#CUs, LDS padded => 1 blk/CU, all co-resident (flag barriers).

#define NN 8192
#define EE 262144
#define THREADS 1024
#define SORTB 64                 // blocks per sort team
#define EPB (EE / SORTB)         // 4096 edges per sort block (4/thread)
#define NB 256                   // buckets = groups = chain blocks
#define CPB (NN / NB)            // 32 cols per chain block
#define GROWS 32                 // rows per scatter group
#define NBLK 256
#define MAGIC 0x5CA1AB1Eu        // != 0xAAAAAAAA ws poison, != 0

typedef unsigned long long u64;

#define LOAD_AU(p)    __hip_atomic_load((p),  __ATOMIC_RELAXED, __HIP_MEMORY_SCOPE_AGENT)
#define STORE_AU(p,v) __hip_atomic_store((p), (v), __ATOMIC_RELAXED, __HIP_MEMORY_SCOPE_AGENT)

// raw barrier: drain DS only (NOT vmcnt) — lets global stores stream across rows
#define LBAR() do { asm volatile("s_waitcnt lgkmcnt(0)" ::: "memory"); \
                    __builtin_amdgcn_s_barrier(); \
                    __builtin_amdgcn_sched_barrier(0); } while (0)

// LDS arena: one member live at a time (phases separated by barriers/syncs).
union SM {
    struct { unsigned cnt[SORTB * NB]; unsigned hist[NB]; unsigned bst[NB + 1];
             unsigned offs[NB]; } so;                                  // ~67 KB
    struct { float acc[CPB]; float dem[CPB]; } c;                      // 256 B
    struct { float img[2 * NN]; u64 eL[2048]; } s;                     // 80 KB
    char pad[90112];                                                   // 1 blk/CU
};

// nblk(<=64)-party: set own word + poll (caller __syncthreads first: vmcnt drain).
__device__ __forceinline__ void flag_barrier_n(unsigned* fl, int idx, int tid, int nblk) {
    if (tid == 0) STORE_AU(&fl[idx], MAGIC);
    asm volatile("" ::: "memory");
    if (tid < 64) {
        for (;;) {
            unsigned f = (tid < nblk) ? LOAD_AU(&fl[tid]) : MAGIC;
            if (__all(f == MAGIC)) break;
            __builtin_amdgcn_s_sleep(2);
        }
    }
    asm volatile("" ::: "memory");
    __syncthreads();
}

// 256-party: set own word + poll 4 words/lane.
__device__ __forceinline__ void flag_barrier_256(unsigned* fl, int idx, int tid) {
    if (tid == 0) STORE_AU(&fl[idx], MAGIC);
    asm volatile("" ::: "memory");
    if (tid < 64) {
        for (;;) {
            unsigned a = LOAD_AU(&fl[tid]);
            unsigned b = LOAD_AU(&fl[tid + 64]);
            unsigned c = LOAD_AU(&fl[tid + 128]);
            unsigned d = LOAD_AU(&fl[tid + 192]);
            if (__all(a == MAGIC && b == MAGIC && c == MAGIC && d == MAGIC)) break;
            __builtin_amdgcn_s_sleep(2);
        }
    }
    asm volatile("" ::: "memory");
    __syncthreads();
}

// passive wait on nblk(<=64) words. SLP: s_sleep ticks, compile-time literal.
template <int SLP>
__device__ __forceinline__ void wait_flags_n(unsigned* fl, int tid, int nblk) {
    if (tid < 64) {
        for (;;) {
            unsigned f = (tid < nblk) ? LOAD_AU(&fl[tid]) : MAGIC;
            if (__all(f == MAGIC)) break;
            __builtin_amdgcn_s_sleep(SLP);
        }
    }
    asm volatile("" ::: "memory");
    __syncthreads();
}

__global__ void __launch_bounds__(THREADS) mega(
        const float* __restrict__ values, const float* __restrict__ dem,
        const int* __restrict__ rows, const int* __restrict__ cols,
        u64* __restrict__ se,        // EE col-sorted: row13 | coff5<<13 | v<<32
        u64* __restrict__ se2,       // EE row-sorted: col13 | rl5<<13  | v<<32
        float* __restrict__ adjF,    // 9*NN floats (slots 1..8)
        float* __restrict__ adj9f,   // NN floats (= A10)
        unsigned* __restrict__ cnt,  // SORTB*NB
        unsigned* __restrict__ cnt2, // SORTB*NB
        unsigned* __restrict__ bstart,   // NB+1
        unsigned* __restrict__ gstart,   // NB+1
        unsigned* __restrict__ flagsC, unsigned* __restrict__ flagsR,
        unsigned* __restrict__ flagsE, unsigned* __restrict__ flagsR2,
        unsigned* __restrict__ flagsK,   // 9*NB
        float* __restrict__ out) {
    __shared__ SM sm;
    __shared__ float a9[GROWS];
    const int bid = blockIdx.x, tid = threadIdx.x;

    if (bid < SORTB) {
        // ============ col-sort team: bucket = col>>5 (256 buckets) ============
        if (tid < NB) sm.so.hist[tid] = 0;
        __syncthreads();
        const int4* c4 = (const int4*)(cols + bid * EPB);
        int4 ca = c4[tid];                            // 4 edges/thread
        atomicAdd(&sm.so.hist[ca.x >> 5], 1u);  atomicAdd(&sm.so.hist[ca.y >> 5], 1u);
        atomicAdd(&sm.so.hist[ca.z >> 5], 1u);  atomicAdd(&sm.so.hist[ca.w >> 5], 1u);
        __syncthreads();
        if (tid < NB) STORE_AU(&cnt[bid * NB + tid], sm.so.hist[tid]);
        __syncthreads();                              // drain cnt
        flag_barrier_n(flagsC, bid, tid, SORTB);

        #pragma unroll
        for (int j = 0; j < (SORTB * NB) / THREADS; ++j)
            sm.so.cnt[tid + j * THREADS] = LOAD_AU(&cnt[tid + j * THREADS]);
        __syncthreads();
        if (tid < NB) {
            unsigned t = 0;
            for (int b = 0; b < SORTB; ++b) t += sm.so.cnt[b * NB + tid];
            sm.so.hist[tid] = t;
        }
        __syncthreads();
        if (tid == 0) {
            unsigned run = 0;
            for (int k = 0; k < NB; ++k) { sm.so.bst[k] = run; run += sm.so.hist[k]; }
            sm.so.bst[NB] = run;
        }
        __syncthreads();
        if (tid < NB) {
            unsigned off = sm.so.bst[tid];
            for (int b = 0; b < bid; ++b) off += sm.so.cnt[b * NB + tid];
            sm.so.offs[tid] = off;
        }
        if (bid == 0 && tid <= NB) STORE_AU(&bstart[tid], sm.so.bst[tid]);
        __syncthreads();

        {   // push: meta = row | (col&31)<<13, value hi32
            const int4*   r4 = (const int4*)(rows + bid * EPB);
            const float4* v4 = (const float4*)(values + bid * EPB);
            int4 ra = r4[tid];  float4 va = v4[tid];
            #define PUSHC(R, C, V) do {                                        \
                unsigned dst_ = atomicAdd(&sm.so.offs[(C) >> 5], 1u);          \
                u64 w_ = (unsigned)((R) | (((C) & 31) << 13))                  \
                       | ((u64)__float_as_uint(V) << 32);                      \
                STORE_AU(&se[dst_], w_);                                       \
            } while (0)
            PUSHC(ra.x, ca.x, va.x);  PUSHC(ra.y, ca.y, va.y);
            PUSHC(ra.z, ca.z, va.z);  PUSHC(ra.w, ca.w, va.w);
            #undef PUSHC
        }
        __syncthreads();                              // drain se + bstart
        flag_barrier_n(flagsE, bid, tid, SORTB);      // col-sort complete
    } else if (bid < 2 * SORTB) {
        // ============ row-sort team: group = row>>5 (256 groups) ============
        const int b2 = bid - SORTB;
        if (tid < NB) sm.so.hist[tid] = 0;
        __syncthreads();
        const int4* r4 = (const int4*)(rows + b2 * EPB);
        int4 ra = r4[tid];
        atomicAdd(&sm.so.hist[ra.x >> 5], 1u);  atomicAdd(&sm.so.hist[ra.y >> 5], 1u);
        atomicAdd(&sm.so.hist[ra.z >> 5], 1u);  atomicAdd(&sm.so.hist[ra.w >> 5], 1u);
        __syncthreads();
        if (tid < NB) STORE_AU(&cnt2[b2 * NB + tid], sm.so.hist[tid]);
        __syncthreads();
        flag_barrier_n(flagsR, b2, tid, SORTB);

        #pragma unroll
        for (int j = 0; j < (SORTB * NB) / THREADS; ++j)
            sm.so.cnt[tid + j * THREADS] = LOAD_AU(&cnt2[tid + j * THREADS]);
        __syncthreads();
        if (tid < NB) {
            unsigned t = 0;
            for (int b = 0; b < SORTB; ++b) t += sm.so.cnt[b * NB + tid];
            sm.so.hist[tid] = t;
        }
        __syncthreads();
        if (tid == 0) {
            unsigned run = 0;
            for (int k = 0; k < NB; ++k) { sm.so.bst[k] = run; run += sm.so.hist[k]; }
            sm.so.bst[NB] = run;
        }
        __syncthreads();
        if (tid < NB) {
            unsigned off = sm.so.bst[tid];
            for (int b = 0; b < b2; ++b) off += sm.so.cnt[b * NB + tid];
            sm.so.offs[tid] = off;
        }
        if (b2 == 0 && tid <= NB) STORE_AU(&gstart[tid], sm.so.bst[tid]);
        __syncthreads();

        {   // push: meta = col | (row&31)<<13, value hi32
            const int4*   c4 = (const int4*)(cols + b2 * EPB);
            const float4* v4 = (const float4*)(values + b2 * EPB);
            int4 ca = c4[tid];  float4 va = v4[tid];
            #define PUSHR(R, C, V) do {                                        \
                unsigned dst_ = atomicAdd(&sm.so.offs[(R) >> 5], 1u);          \
                u64 w_ = (unsigned)((C) | (((R) & 31) << 13))                  \
                       | ((u64)__float_as_uint(V) << 32);                      \
                STORE_AU(&se2[dst_], w_);                                      \
            } while (0)
            PUSHR(ra.x, ca.x, va.x);  PUSHR(ra.y, ca.y, va.y);
            PUSHR(ra.z, ca.z, va.z);  PUSHR(ra.w, ca.w, va.w);
            #undef PUSHR
        }
        __syncthreads();                              // drain se2 + gstart
        if (tid == 0) STORE_AU(&flagsR2[b2], MAGIC);
        asm volatile("" ::: "memory");
        wait_flags_n<4>(flagsE, tid, SORTB);          // then join the chain
    } else {
        // ============ parked until col-sort done ============
        wait_flags_n<8>(flagsE, tid, SORTB);
    }

    // ================= chain: ALL 256 blocks, block owns bucket `bid` =======
    const int bs = (int)LOAD_AU(&bstart[bid]);
    const int be = (int)LOAD_AU(&bstart[bid + 1]);
    const int ne = be - bs;
    u64 e0 = 0, e1 = 0;                               // ~1024 edges -> 1-2 regs
    if (tid < ne)           e0 = LOAD_AU(&se[bs + tid]);
    if (THREADS + tid < ne) e1 = LOAD_AU(&se[bs + THREADS + tid]);
    if (tid < CPB) sm.c.dem[tid] = dem[bid * CPB + tid];

    for (int s = 1; s <= 9; ++s) {
        if (tid < CPB) sm.c.acc[tid] = 0.f;
        __syncthreads();

        #define EDGE(W) do {                                                   \
            unsigned m_ = (unsigned)(W);                                       \
            float v_ = __uint_as_float((unsigned)((W) >> 32));                 \
            int r_ = m_ & (NN - 1);                                            \
            float a_ = (s == 1) ? fmaxf(-dem[r_], 0.f)                         \
                                : LOAD_AU(&adjF[(size_t)(s - 1) * NN + r_]);   \
            atomicAdd(&sm.c.acc[(m_ >> 13) & 31], v_ * a_);                    \
        } while (0)
        if (tid < ne)           EDGE(e0);
        if (THREADS + tid < ne) EDGE(e1);
        for (int i = bs + 2 * THREADS + tid; i < be; i += THREADS) {  // ~never
            u64 w = LOAD_AU(&se[i]);
            EDGE(w);
        }
        #undef EDGE
        __syncthreads();

        if (tid < CPB) {
            float r = fmaxf(sm.c.acc[tid] - sm.c.dem[tid], 0.f);
            if (s < 9) STORE_AU(&adjF[(size_t)s * NN + bid * CPB + tid], r);
            else       STORE_AU(&adj9f[bid * CPB + tid], r);
        }
        __syncthreads();                              // drain publish
        flag_barrier_256(flagsK + (s - 1) * NB, bid, tid);
    }
    // stage-9 barrier == all adj9f visible. Uniform last prereq:
    wait_flags_n<2>(flagsR2, tid, SORTB);             // se2/gstart (long ready)

    // ======= scatter: block streams row-group `bid`, img double-buffered ====
    {
        const int g = bid;
        const unsigned gs = LOAD_AU(&gstart[g]), ge = LOAD_AU(&gstart[g + 1]);
        const unsigned n = ge - gs;
        const unsigned ncp = n < 2048u ? n : 2048u;
        if (tid < GROWS) a9[tid] = LOAD_AU(&adj9f[g * GROWS + tid]);
        __syncthreads();                              // a9 + LDS transition

        for (unsigned i = tid; i < ncp; i += THREADS) {   // premultiply
            u64 w = LOAD_AU(&se2[gs + i]);
            unsigned m = (unsigned)w;
            float v = __uint_as_float((unsigned)(w >> 32));
            sm.s.eL[i] = (u64)m | ((u64)__float_as_uint(v * a9[(m >> 13) & 31]) << 32);
        }
        __syncthreads();

        const float4 z4 = make_float4(0.f, 0.f, 0.f, 0.f);
        for (int r = 0; r < GROWS; ++r) {
            float* im = sm.s.img + (r & 1) * NN;
            ((float4*)im)[tid]        = z4;           // zero 32KB image
            ((float4*)im)[tid + 1024] = z4;
            LBAR();
            for (unsigned i = tid; i < ncp; i += THREADS) {
                u64 w = sm.s.eL[i];
                unsigned m = (unsigned)w;
                if (((m >> 13) & 31) == (unsigned)r)
                    atomicAdd(&im[m & (NN - 1)], __uint_as_float((unsigned)(w >> 32)));
            }
            for (unsigned i = 2048u + tid; i < n; i += THREADS) {   // ~never
                u64 w = LOAD_AU(&se2[gs + i]);
                unsigned m = (unsigned)w;
                if (((m >> 13) & 31) == (unsigned)r)
                    atomicAdd(&im[m & (NN - 1)],
                              __uint_as_float((unsigned)(w >> 32)) * a9[r]);
            }
            LBAR();
            float4 w0 = ((const float4*)im)[tid];     // ds_read, lgkm-waited
            float4 w1 = ((const float4*)im)[tid + 1024];
            float4* o4 = (float4*)(out + (size_t)(g * GROWS + r) * NN);
            o4[tid]        = w0;                      // stores stream (no drain)
            o4[tid + 1024] = w1;
        }
    }
}

extern "C" void kernel_launch(void* const* d_in, const int* in_sizes, int n_in,
                              void* d_out, int out_size, void* d_ws, size_t ws_size,
                              hipStream_t stream) {
    const float* values = (const float*)d_in[0];
    const float* dem    = (const float*)d_in[1];
    const int*   rows   = (const int*)d_in[2];
    const int*   cols   = (const int*)d_in[3];
    float* out = (float*)d_out;

    u64*      se      = (u64*)d_ws;                       // 2 MB
    u64*      se2     = se + (size_t)EE;                  // 2 MB
    float*    adjF    = (float*)(se2 + (size_t)EE);       // 288 KB
    float*    adj9f   = adjF + 9L * NN;                   // 32 KB
    unsigned* cnt     = (unsigned*)(adj9f + NN);          // 64 KB
    unsigned* cnt2    = cnt + SORTB * NB;                 // 64 KB
    unsigned* bstart  = cnt2 + SORTB * NB;                // 257 (+pad)
    unsigned* gstart  = bstart + 320;                     // 257 (+pad)
    unsigned* flagsC  = gstart + 320;
    unsigned* flagsR  = flagsC + 64;
    unsigned* flagsE  = flagsR + 64;
    unsigned* flagsR2 = flagsE + 64;
    unsigned* flagsK  = flagsR2 + 64;                     // 9*256

    mega<<<NBLK, THREADS, 0, stream>>>(
        values, dem, rows, cols, se, se2, adjF, adj9f, cnt, cnt2,
        bstart, gstart, flagsC, flagsR, flagsE, flagsR2, flagsK, out);
}